// Round 9
// baseline (80.793 us; speedup 1.0000x reference)
//
#include <hip/hip_runtime.h>
#include <hip/hip_bf16.h>

#define B_ROWS 8192
#define DIM 256
#define C_CLS 5994
#define N_CHUNK 188       // 6016 / 32
#define NSPL 8
#define H_HALF 4096
#define SCALE_F 30.0f
#define MAXL 30.0f
#define EXPC 43.2808512266689f   // 30*log2(e):  exp(30x-30) = exp2(EXPC*x - EXPC)

#if defined(__has_builtin)
#if __has_builtin(__builtin_amdgcn_exp2f)
#define EXP2(x) __builtin_amdgcn_exp2f(x)
#endif
#endif
#ifndef EXP2
#define EXP2(x) exp2f(x)
#endif

typedef _Float16 half8 __attribute__((ext_vector_type(8)));
typedef float f32x16 __attribute__((ext_vector_type(16)));

// ---------------- pack: norms + blocked f16 layouts + accum zero ---------
// Blocked layout per 32-row tile (16 KB): half_off = tile*8192 + k*512 + lh*256 + l31*8 + idx
// A wave's MFMA fragment load (fixed k) is lane-linear -> one contiguous 1 KB load.
__global__ __launch_bounds__(256)
void k_pack(const float* __restrict__ emb, const float* __restrict__ W,
            _Float16* __restrict__ en_blk, _Float16* __restrict__ wn_blk,
            float* __restrict__ rne, float* __restrict__ rnw,
            float* __restrict__ accum) {
  __shared__ float ssm[256];
  __shared__ float rnl[32];
  const int b = blockIdx.x;
  const int t = threadIdx.x;
  if (b == 0 && t < 8) accum[t] = 0.f;   // accum[0..3] + counter(+pad), zeroed every call
  const bool isW = b >= (B_ROWS/32);
  const int tile = isW ? b - (B_ROWS/32) : b;
  const int l31 = t & 31;
  const int row = tile*32 + l31;
  const float* __restrict__ src = isW ? W : emb;
  const bool rv = (!isW) || (row < C_CLS);

  float v[4][8];
  float ss = 0.f;
  #pragma unroll
  for (int i=0;i<4;i++) {
    const int d0 = ((t>>6) + i*4)*16 + ((t>>5)&1)*8;
    if (rv) {
      float4 x0 = *(const float4*)(src + (size_t)row*DIM + d0);
      float4 x1 = *(const float4*)(src + (size_t)row*DIM + d0 + 4);
      v[i][0]=x0.x; v[i][1]=x0.y; v[i][2]=x0.z; v[i][3]=x0.w;
      v[i][4]=x1.x; v[i][5]=x1.y; v[i][6]=x1.z; v[i][7]=x1.w;
      ss += x0.x*x0.x + x0.y*x0.y + x0.z*x0.z + x0.w*x0.w
          + x1.x*x1.x + x1.y*x1.y + x1.z*x1.z + x1.w*x1.w;
    } else {
      #pragma unroll
      for (int j=0;j<8;j++) v[i][j] = 0.f;
    }
  }
  ssm[t] = ss;
  __syncthreads();
  if (t < 32) {
    float s = 0.f;
    #pragma unroll
    for (int j=0;j<8;j++) s += ssm[t + j*32];
    float rn = 1.0f/(sqrtf(s) + 1e-12f);
    rnl[t] = rn;
    int rw = tile*32 + t;
    if (!isW) rne[rw] = rn;
    else if (rw < C_CLS) rnw[rw] = rn;
  }
  __syncthreads();
  const float rn = rnl[l31];
  _Float16* __restrict__ dst = (isW ? wn_blk : en_blk) + (size_t)tile*8192;
  #pragma unroll
  for (int i=0;i<4;i++) {
    half8 h;
    #pragma unroll
    for (int j=0;j<8;j++) h[j] = (_Float16)(v[i][j]*rn);
    *(half8*)(dst + t*8 + i*2048) = h;   // coalesced 16B stores
  }
}

// ---------------- main fused GEMM + online softmax-stats ----------------
// grid = 32 panels x 8 splits = 256 blocks (1/CU); block = 256 (4 waves).
// Each wave owns 64 rows (two 32-row A-tiles), two interleaved MFMA chains
// against shared B fragments -> half the per-CU L1 traffic of 32-row waves.
// Barrier-free; B register-double-buffered (half-chunks); peeled last iter.
__global__ __launch_bounds__(256, 1)
void k_logits(const _Float16* __restrict__ en_blk, const _Float16* __restrict__ wn_blk,
              float* __restrict__ psum, unsigned* __restrict__ pkey) {
  const int split = blockIdx.x & (NSPL-1);
  const int panel = blockIdx.x / NSPL;
  const int wid  = threadIdx.x >> 6;
  const int lane = threadIdx.x & 63;
  const int l31  = lane & 31;
  const int lh   = lane >> 5;
  const int t64  = panel*4 + wid;            // 64-row tile index (0..127)

  // A fragments: 2 tiles x 16 contiguous 1 KB wave-loads, resident all loop
  half8 a0[16], a1[16];
  {
    const _Float16* ab = en_blk + (size_t)t64*16384 + lane*8;
    #pragma unroll
    for (int k=0;k<16;k++) a0[k] = *(const half8*)(ab + k*512);
    #pragma unroll
    for (int k=0;k<16;k++) a1[k] = *(const half8*)(ab + 8192 + k*512);
  }

  float ssum0[16], ssum1[16]; unsigned key0[16], key1[16];
  #pragma unroll
  for (int r=0;r<16;r++){ ssum0[r]=0.f; key0[r]=0u; ssum1[r]=0.f; key1[r]=0u; }

  const int nit = (N_CHUNK - split + NSPL - 1) / NSPL;   // 24 or 23
  const _Float16* p = wn_blk + (size_t)split*8192 + lane*8;
  const ptrdiff_t STEP = (ptrdiff_t)NSPL*8192;

  half8 b0[8], b1[8];
  #pragma unroll
  for (int k=0;k<8;k++) b0[k] = *(const half8*)(p + k*512);
  #pragma unroll
  for (int k=0;k<8;k++) b1[k] = *(const half8*)(p + (k+8)*512);

  unsigned colu = (unsigned)(split*32 + l31);
  for (int it = 0; it < nit-1; ++it) {
    const _Float16* pn = p + STEP;
    f32x16 acc0 = {}, acc1 = {};
    #pragma unroll
    for (int k=0;k<8;k++) {
      acc0 = __builtin_amdgcn_mfma_f32_32x32x16_f16(a0[k], b0[k], acc0, 0,0,0);
      acc1 = __builtin_amdgcn_mfma_f32_32x32x16_f16(a1[k], b0[k], acc1, 0,0,0);
    }
    #pragma unroll
    for (int k=0;k<8;k++) b0[k] = *(const half8*)(pn + k*512);
    #pragma unroll
    for (int k=0;k<8;k++) {
      acc0 = __builtin_amdgcn_mfma_f32_32x32x16_f16(a0[k+8], b1[k], acc0, 0,0,0);
      acc1 = __builtin_amdgcn_mfma_f32_32x32x16_f16(a1[k+8], b1[k], acc1, 0,0,0);
    }
    #pragma unroll
    for (int k=0;k<8;k++) b1[k] = *(const half8*)(pn + (k+8)*512);
    // epilogue: pad cols are zero rows -> x=0 -> exp2(-43.3)~1e-13, negligible
    #pragma unroll
    for (int r=0;r<16;r++) {
      float x = acc0[r];
      ssum0[r] += EXP2(fmaf(x, EXPC, -EXPC));
      unsigned ky = (__float_as_uint(x + 2.0f) & 0xFFFFE000u) | colu;  // x+2>0: monotone
      key0[r] = ky > key0[r] ? ky : key0[r];
      float x1 = acc1[r];
      ssum1[r] += EXP2(fmaf(x1, EXPC, -EXPC));
      unsigned ky1 = (__float_as_uint(x1 + 2.0f) & 0xFFFFE000u) | colu;
      key1[r] = ky1 > key1[r] ? ky1 : key1[r];
    }
    colu += NSPL*32;
    p = pn;
  }
  { // last chunk, no prefetch
    f32x16 acc0 = {}, acc1 = {};
    #pragma unroll
    for (int k=0;k<8;k++) {
      acc0 = __builtin_amdgcn_mfma_f32_32x32x16_f16(a0[k], b0[k], acc0, 0,0,0);
      acc1 = __builtin_amdgcn_mfma_f32_32x32x16_f16(a1[k], b0[k], acc1, 0,0,0);
    }
    #pragma unroll
    for (int k=0;k<8;k++) {
      acc0 = __builtin_amdgcn_mfma_f32_32x32x16_f16(a0[k+8], b1[k], acc0, 0,0,0);
      acc1 = __builtin_amdgcn_mfma_f32_32x32x16_f16(a1[k+8], b1[k], acc1, 0,0,0);
    }
    #pragma unroll
    for (int r=0;r<16;r++) {
      float x = acc0[r];
      ssum0[r] += EXP2(fmaf(x, EXPC, -EXPC));
      unsigned ky = (__float_as_uint(x + 2.0f) & 0xFFFFE000u) | colu;
      key0[r] = ky > key0[r] ? ky : key0[r];
      float x1 = acc1[r];
      ssum1[r] += EXP2(fmaf(x1, EXPC, -EXPC));
      unsigned ky1 = (__float_as_uint(x1 + 2.0f) & 0xFFFFE000u) | colu;
      key1[r] = ky1 > key1[r] ? ky1 : key1[r];
    }
  }

  // reduce across the 32 lanes (cols); offsets 1..16 stay within each half
  #pragma unroll
  for (int off=1; off<32; off<<=1) {
    #pragma unroll
    for (int r=0;r<16;r++) {
      ssum0[r] += __shfl_xor(ssum0[r], off);
      unsigned o0 = __shfl_xor(key0[r], off);
      key0[r] = o0 > key0[r] ? o0 : key0[r];
      ssum1[r] += __shfl_xor(ssum1[r], off);
      unsigned o1 = __shfl_xor(key1[r], off);
      key1[r] = o1 > key1[r] ? o1 : key1[r];
    }
  }
  if (l31 == 0) {
    const int rowbase = t64*64;
    #pragma unroll
    for (int r=0;r<16;r++) {
      int rr = (r&3) + 8*(r>>2) + 4*lh;
      psum[split*B_ROWS + rowbase + rr] = ssum0[r];
      pkey[split*B_ROWS + rowbase + rr] = key0[r];
      psum[split*B_ROWS + rowbase + 32 + rr] = ssum1[r];
      pkey[split*B_ROWS + rowbase + 32 + rr] = key1[r];
    }
  }
}

// ---------------- tail: das + merge + finalize (completion counter) ------
__global__ __launch_bounds__(256)
void k_tail(const float* __restrict__ emb, const float* __restrict__ W,
            const int* __restrict__ y, const int* __restrict__ y_d,
            const float* __restrict__ rne, const float* __restrict__ rnw,
            const float* __restrict__ psum, const unsigned* __restrict__ pkey,
            float* __restrict__ accum, float* __restrict__ out) {
  __shared__ float s0[4], s1[4];
  const int wid = threadIdx.x >> 6, lane = threadIdx.x & 63;
  if (blockIdx.x < 128) {
    // ----- merge: per-row exact y-logit + combine partials -----
    float lacc = 0.f, cacc = 0.f;
    for (int row = blockIdx.x*4 + wid; row < B_ROWS; row += 512) {
      const int yc = y[row];
      float4 e = *(const float4*)(emb + (size_t)row*DIM + lane*4);
      float4 w = *(const float4*)(W + (size_t)yc*DIM + lane*4);
      float d = e.x*w.x + e.y*w.y + e.z*w.z + e.w*w.w;
      #pragma unroll
      for (int off=1; off<64; off<<=1) d += __shfl_xor(d, off);
      float S = 0.f; unsigned km = 0u;
      if (lane < NSPL) {
        S = psum[lane*B_ROWS + row];
        km = pkey[lane*B_ROWS + row];
      }
      #pragma unroll
      for (int off=1; off<NSPL; off<<=1) {
        S += __shfl_xor(S, off);
        unsigned o = __shfl_xor(km, off);
        if (o > km) km = o;
      }
      if (lane == 0) {
        float ly = SCALE_F * d * rne[row] * rnw[yc];
        lacc += MAXL + logf(S) - ly;
        cacc += ((km & 0x1FFFu) == (unsigned)yc) ? 1.f : 0.f;
      }
    }
    if (lane == 0) { s0[wid] = lacc; s1[wid] = cacc; }
    __syncthreads();
    if (threadIdx.x == 0) {
      atomicAdd(&accum[0], s0[0]+s0[1]+s0[2]+s0[3]);
      atomicAdd(&accum[1], s1[0]+s1[1]+s1[2]+s1[3]);
    }
  } else {
    // ----- das: contrastive pair distances (f32, from raw emb) -----
    float a2 = 0.f, a3 = 0.f;
    for (int i = (blockIdx.x-128)*4 + wid; i < H_HALF; i += 256) {
      const int j = (i+1) & (H_HALF-1);
      const int di = y_d[i], dj = y_d[j], dih = y_d[i + H_HALF];
      float4 z = {0.f,0.f,0.f,0.f};
      float4 mi = (di==0)  ? *(const float4*)(emb + (size_t)i*DIM + lane*4) : z;
      float4 mj = (dj==0)  ? *(const float4*)(emb + (size_t)j*DIM + lane*4) : z;
      float4 ti = (dih!=0) ? *(const float4*)(emb + (size_t)(i+H_HALF)*DIM + lane*4)
                           : ((di!=0) ? *(const float4*)(emb + (size_t)i*DIM + lane*4) : z);
      float px = mi.x-mj.x, py = mi.y-mj.y, pz = mi.z-mj.z, pw = mi.w-mj.w;
      float nx = mi.x-ti.x, ny = mi.y-ti.y, nz = mi.z-ti.z, nw = mi.w-ti.w;
      float sp = px*px+py*py+pz*pz+pw*pw;
      float sn = nx*nx+ny*ny+nz*nz+nw*nw;
      #pragma unroll
      for (int off=1; off<64; off<<=1) { sp += __shfl_xor(sp, off); sn += __shfl_xor(sn, off); }
      if (lane == 0) {
        float dp = sqrtf(sp), dn = sqrtf(sn);
        float m = fmaxf(2.0f - dp, 0.f);
        a2 += m*m + dn*dn;
        a3 += dp + dn;
      }
    }
    if (lane == 0) { s0[wid] = a2; s1[wid] = a3; }
    __syncthreads();
    if (threadIdx.x == 0) {
      atomicAdd(&accum[2], s0[0]+s0[1]+s0[2]+s0[3]);
      atomicAdd(&accum[3], s1[0]+s1[1]+s1[2]+s1[3]);
    }
  }
  // ----- finalize: last block to finish writes the 4 outputs -----
  if (threadIdx.x == 0) {
    __threadfence();                                   // publish accum adds
    unsigned* cnt = (unsigned*)(accum + 4);
    unsigned done = atomicAdd(cnt, 1u);
    if (done == 191u) {                                // last of 192 blocks
      float v0 = atomicAdd(&accum[0], 0.f);            // coherent reads
      float v1 = atomicAdd(&accum[1], 0.f);
      float v2 = atomicAdd(&accum[2], 0.f);
      float v3 = atomicAdd(&accum[3], 0.f);
      out[0] = v0 * (1.0f/B_ROWS);  // loss_c
      out[1] = v2 * (1.0f/B_ROWS);  // das_loss
      out[2] = v1 * (1.0f/B_ROWS);  // acc
      out[3] = v3 * (1.0f/B_ROWS);  // das_dist_mean
    }
  }
}

extern "C" void kernel_launch(void* const* d_in, const int* in_sizes, int n_in,
                              void* d_out, int out_size, void* d_ws, size_t ws_size,
                              hipStream_t stream) {
  const float* emb = (const float*)d_in[0];
  const float* W   = (const float*)d_in[1];
  const int*   y   = (const int*)d_in[2];
  const int*   y_d = (const int*)d_in[3];

  char* ws = (char*)d_ws;
  const size_t EN_OFF   = 0;                                  // 256 tiles * 16 KB = 4,194,304
  const size_t WN_OFF   = EN_OFF  + (size_t)256*16384;        // 188 tiles * 16 KB = 3,080,192
  const size_t RNE_OFF  = WN_OFF  + (size_t)N_CHUNK*16384;    // 32,768
  const size_t RNW_OFF  = RNE_OFF + (size_t)B_ROWS*4;         // 24,064 (6016 floats)
  const size_t PSUM_OFF = RNW_OFF + 24064;                    // 8*8192*4 = 262,144
  const size_t PKEY_OFF = PSUM_OFF + (size_t)NSPL*B_ROWS*4;   // 8*8192*4 = 262,144
  const size_t ACC_OFF  = PKEY_OFF + (size_t)NSPL*B_ROWS*4;   // 32 (4 floats + cnt + pad)

  _Float16* en_blk = (_Float16*)(ws + EN_OFF);
  _Float16* wn_blk = (_Float16*)(ws + WN_OFF);
  float*    rne   = (float*)(ws + RNE_OFF);
  float*    rnw   = (float*)(ws + RNW_OFF);
  float*    psum  = (float*)(ws + PSUM_OFF);
  unsigned* pkey  = (unsigned*)(ws + PKEY_OFF);
  float*    accum = (float*)(ws + ACC_OFF);

  k_pack<<<B_ROWS/32 + N_CHUNK, 256, 0, stream>>>(emb, W, en_blk, wn_blk, rne, rnw, accum);
  k_logits<<<32*NSPL, 256, 0, stream>>>(en_blk, wn_blk, psum, pkey);
  k_tail<<<192, 256, 0, stream>>>(emb, W, y, y_d, rne, rnw, psum, pkey, accum, (float*)d_out);
}